// Round 6
// baseline (754.061 us; speedup 1.0000x reference)
//
#include <hip/hip_runtime.h>

#define B_TOT   4096
#define T_STEPS 512
#define IN_F    5
#define D_FC    32
#define D_H     64
#define NT      16      // N-tiles: 256 gate columns / 16
#define ROWH    104     // f16 elems per Hcat row (96 + 8 pad; rows 16B-aligned)

typedef _Float16 h8 __attribute__((ext_vector_type(8)));
typedef float    f4 __attribute__((ext_vector_type(4)));

#define LOG2E    1.4426950408889634f
#define TWOLOG2E 2.8853900817779268f

__device__ __forceinline__ float fexp2(float x) { return __builtin_amdgcn_exp2f(x); }
__device__ __forceinline__ float frcp(float x)  { return __builtin_amdgcn_rcpf(x); }

// One wave = one block = 4 batches, fully autonomous: no __syncthreads anywhere.
// Hcat row layout (f16): [0..4]=x_t, [5..31]=0, [32..95]=h(t-1). Batch b at row 4b.
__global__ __launch_bounds__(64, 1) void lstm_wave(
    const float* __restrict__ x,
    const float* __restrict__ W0,
    const float* __restrict__ b0,
    const float* __restrict__ W_ih,
    const float* __restrict__ W_hh,
    const float* __restrict__ b_ih,
    const float* __restrict__ b_hh,
    const float* __restrict__ Wo,
    const float* __restrict__ bo,
    float* __restrict__ out)
{
    __shared__ _Float16 H[16][ROWH];

    const int lane = threadIdx.x;       // blockDim = 64: one wave
    const int col  = lane & 15;
    const int quad = lane >> 4;
    const int bbase = blockIdx.x * 4;   // this wave's 4 batches

    // ---- zero the whole LDS tile (garbage rows must multiply as 0) ----
    {
        unsigned* p = (unsigned*)&H[0][0];
        #pragma unroll
        for (int i = 0; i < 13; ++i)            // 16*104/2 = 832 dwords
            p[lane + 64 * i] = 0u;
    }

    // ---- fused weights as resident B-fragments ----
    // B[k=quad*8+jj][n=nt*16+col], k<32: W_xg (x-path, = W_ih[:, :32] @ W0), else W_hh
    h8 Bf[NT][3];
    #pragma unroll
    for (int nt = 0; nt < NT; ++nt) {
        const int n = nt * 16 + col;
        // chunk 0: x-path (only k<5 nonzero)
        h8 f0;
        #pragma unroll
        for (int jj = 0; jj < 8; ++jj) {
            const int k = quad * 8 + jj;
            float s = 0.0f;
            if (k < IN_F) {
                #pragma unroll 1
                for (int m = 0; m < D_FC; ++m)
                    s = fmaf(W_ih[n * D_FC + m], W0[m * IN_F + k], s);
            }
            f0[jj] = (_Float16)s;
        }
        Bf[nt][0] = f0;
        // chunks 1,2: W_hh
        #pragma unroll
        for (int c = 1; c < 3; ++c) {
            h8 f;
            #pragma unroll
            for (int jj = 0; jj < 8; ++jj)
                f[jj] = (_Float16)W_hh[n * D_H + (c - 1) * 32 + quad * 8 + jj];
            Bf[nt][c] = f;
        }
    }

    // ---- fused gate bias (b_ih + b_hh + W_ih[:, :32] @ b0), pre-scaled for exp2 ----
    float bsc[NT];
    #pragma unroll
    for (int nt = 0; nt < NT; ++nt) {
        const int n = nt * 16 + col;
        float bf = b_ih[n] + b_hh[n];
        #pragma unroll 1
        for (int m = 0; m < D_FC; ++m)
            bf = fmaf(W_ih[n * D_FC + m], b0[m], bf);
        bsc[nt] = ((nt >> 2) == 2) ? TWOLOG2E * bf : -LOG2E * bf;
    }

    // ---- x staging: lane (quad,col<5) owns x[batch=bbase+quad][t][col] ----
    const bool xact = (col < IN_F);
    const float* xp = x + (size_t)(bbase + quad) * T_STEPS * IN_F + col;
    if (xact) H[4 * quad][col] = (_Float16)xp[0];      // x(0)
    float xr = xact ? xp[IN_F] : 0.0f;                 // x(1)

    float c_st[4] = {0.0f, 0.0f, 0.0f, 0.0f};
    float hh[4]   = {0.0f, 0.0f, 0.0f, 0.0f};
    const f4 zero4 = {0.0f, 0.0f, 0.0f, 0.0f};

    for (int t = 0; t < T_STEPS; ++t) {
        // A-fragments: A[m=col][k=quad*8+jj] (b128, 16B aligned). In-order DS
        // guarantees these see last iter's h/x writes; no barrier needed.
        const h8 A0 = *(const h8*)&H[col][quad * 8];
        const h8 A1 = *(const h8*)&H[col][32 + quad * 8];
        const h8 A2 = *(const h8*)&H[col][64 + quad * 8];

        f4 acc[NT];
        #pragma unroll
        for (int nt = 0; nt < NT; ++nt) {
            f4 a = __builtin_amdgcn_mfma_f32_16x16x32_f16(A0, Bf[nt][0], zero4, 0, 0, 0);
            a = __builtin_amdgcn_mfma_f32_16x16x32_f16(A1, Bf[nt][1], a, 0, 0, 0);
            a = __builtin_amdgcn_mfma_f32_16x16x32_f16(A2, Bf[nt][2], a, 0, 0, 0);
            acc[nt] = a;
        }

        // stage x(t+1) (reads of A0 already ordered before this write)
        if (xact) H[4 * quad][col] = (_Float16)xr;
        // prefetch x(t+2)
        const int tn = (t + 2 < T_STEPS) ? (t + 2) : (T_STEPS - 1);
        xr = xact ? xp[tn * IN_F] : 0.0f;

        // elementwise: lane owns batch=quad, j = jg*16+col (reg 0 = row 4*quad)
        #pragma unroll
        for (int jg = 0; jg < 4; ++jg) {
            const float gi = acc[jg][0];
            const float gf = acc[4 + jg][0];
            const float gg = acc[8 + jg][0];
            const float go = acc[12 + jg][0];
            const float ii = frcp(1.0f + fexp2(fmaf(-LOG2E, gi, bsc[jg])));
            const float ff = frcp(1.0f + fexp2(fmaf(-LOG2E, gf, bsc[4 + jg])));
            const float g_ = fmaf(-2.0f, frcp(1.0f + fexp2(fmaf(TWOLOG2E, gg, bsc[8 + jg]))), 1.0f);
            const float oo = frcp(1.0f + fexp2(fmaf(-LOG2E, go, bsc[12 + jg])));
            c_st[jg] = fmaf(ff, c_st[jg], ii * g_);
            const float th = fmaf(-2.0f, frcp(1.0f + fexp2(TWOLOG2E * c_st[jg])), 1.0f);
            hh[jg] = oo * th;
            H[4 * quad][D_FC + jg * 16 + col] = (_Float16)hh[jg];
        }
    }

    // ---- output head: out[b] = bo + sum_j h_last[b][j]*Wo[j]; reduce over col ----
    float v = 0.0f;
    #pragma unroll
    for (int jg = 0; jg < 4; ++jg)
        v = fmaf(hh[jg], Wo[jg * 16 + col], v);
    v += __shfl_xor(v, 1, 64);
    v += __shfl_xor(v, 2, 64);
    v += __shfl_xor(v, 4, 64);
    v += __shfl_xor(v, 8, 64);
    if (col == 0)
        out[bbase + quad] = v + bo[0];
}

extern "C" void kernel_launch(void* const* d_in, const int* in_sizes, int n_in,
                              void* d_out, int out_size, void* d_ws, size_t ws_size,
                              hipStream_t stream) {
    const float* x    = (const float*)d_in[0];
    const float* W0   = (const float*)d_in[1];
    const float* b0   = (const float*)d_in[2];
    const float* W_ih = (const float*)d_in[3];
    const float* W_hh = (const float*)d_in[4];
    const float* b_ih = (const float*)d_in[5];
    const float* b_hh = (const float*)d_in[6];
    const float* Wo   = (const float*)d_in[7];
    const float* bo   = (const float*)d_in[8];
    float* out = (float*)d_out;

    hipLaunchKernelGGL(lstm_wave, dim3(B_TOT / 4), dim3(64), 0, stream,
                       x, W0, b0, W_ih, W_hh, b_ih, b_hh, Wo, bo, out);
}

// Round 7
// 398.098 us; speedup vs baseline: 1.8942x; 1.8942x over previous
//
#include <hip/hip_runtime.h>

#define B_TOT   4096
#define T_STEPS 512
#define IN_F    5
#define D_FC    32
#define D_H     64
#define NG      2       // ping-pong groups per block
#define GB      8       // batches per group
#define NROW    16      // MFMA M-tile rows (batch b -> row mrow(b))
#define ROWPAD  104     // f16 elems per row (96 + 8 pad; rows stay 16B-aligned)

typedef _Float16 h8 __attribute__((ext_vector_type(8)));
typedef float    f4 __attribute__((ext_vector_type(4)));

#define LOG2E    1.4426950408889634f
#define TWOLOG2E 2.8853900817779268f

__device__ __forceinline__ float fexp2(float x) { return __builtin_amdgcn_exp2f(x); }
__device__ __forceinline__ float frcp(float x)  { return __builtin_amdgcn_rcpf(x); }

// batch b (0..7) -> M-tile row: quads 0..3 each hold 2 valid rows (regs 0,1)
__device__ __forceinline__ int mrow(int b) { return ((b >> 1) << 2) | (b & 1); }

__global__ __launch_bounds__(256, 1) void lstm_mfma(
    const float* __restrict__ x,
    const float* __restrict__ W0,
    const float* __restrict__ b0,
    const float* __restrict__ W_ih,
    const float* __restrict__ W_hh,
    const float* __restrict__ b_ih,
    const float* __restrict__ b_hh,
    const float* __restrict__ Wo,
    const float* __restrict__ bo,
    float* __restrict__ out)
{
    // H[group][buf][row][k]: k 0..31 = h0(t) (fc0 out), 32..95 = h(t-1), f16
    __shared__ _Float16 H[NG][2][NROW][ROWPAD];

    const int tid  = threadIdx.x;
    const int lane = tid & 63;
    const int w    = tid >> 6;      // wave id: owns hidden j in [w*16, w*16+16)
    const int col  = lane & 15;
    const int quad = lane >> 4;
    const int bblk = blockIdx.x * (NG * GB);

    // ---- resident B-fragments (SHARED by both groups) ----
    h8 Bf[4][3];
    #pragma unroll
    for (int q = 0; q < 4; ++q) {
        const int row = q * 64 + w * 16 + col;
        #pragma unroll
        for (int c = 0; c < 3; ++c) {
            h8 f;
            #pragma unroll
            for (int jj = 0; jj < 8; ++jj) {
                const int k = c * 32 + quad * 8 + jj;
                const float wv = (k < D_FC) ? W_ih[row * D_FC + k]
                                            : W_hh[row * D_H + (k - D_FC)];
                f[jj] = (_Float16)wv;
            }
            Bf[q][c] = f;
        }
    }
    // biases pre-scaled for exp2-arg folding: sig -> -LOG2E*b, tanh -> TWOLOG2E*b
    float bsc[4];
    #pragma unroll
    for (int q = 0; q < 4; ++q) {
        const int row = q * 64 + w * 16 + col;
        const float bf = b_ih[row] + b_hh[row];
        bsc[q] = (q == 2) ? TWOLOG2E * bf : -LOG2E * bf;
    }

    // ---- fc0 assignment: thread -> (batch fb, column fc), both groups ----
    const int fb   = tid >> 5;      // 0..7
    const int fc   = tid & 31;      // 0..31
    const int frow = mrow(fb);
    float w0c[IN_F];
    #pragma unroll
    for (int i = 0; i < IN_F; ++i) w0c[i] = W0[fc * IN_F + i];
    const float b0s = b0[fc];

    const float* xA = x + (size_t)(bblk + fb) * T_STEPS * IN_F;
    const float* xB = x + (size_t)(bblk + GB + fb) * T_STEPS * IN_F;

    // ---- zero ALL LDS (garbage rows must stay 0), then seed h0(0) ----
    {
        unsigned* p = (unsigned*)&H[0][0][0][0];
        const int ndw = NG * 2 * NROW * ROWPAD / 2;   // 3328 dwords
        for (int i = tid; i < ndw; i += 256) p[i] = 0u;
    }
    __syncthreads();
    {
        float a = b0s, b = b0s;
        #pragma unroll
        for (int i = 0; i < IN_F; ++i) {
            a = fmaf(w0c[i], xA[i], a);
            b = fmaf(w0c[i], xB[i], b);
        }
        H[0][0][frow][fc] = (_Float16)a;
        H[1][0][frow][fc] = (_Float16)b;
    }
    // prefetch x(t=1)
    float xrA[IN_F], xrB[IN_F];
    #pragma unroll
    for (int i = 0; i < IN_F; ++i) { xrA[i] = xA[IN_F + i]; xrB[i] = xB[IN_F + i]; }

    // cell state: lane owns (batch quad*2+r, j=w*16+col) for r=0,1, per group
    float cA[2] = {0.0f, 0.0f}, cB[2] = {0.0f, 0.0f};
    const f4 zero4 = {0.0f, 0.0f, 0.0f, 0.0f};

    __syncthreads();

    for (int t = 0; t < T_STEPS; ++t) {
        const int rp = t & 1, wp = rp ^ 1;

        // A-fragments for BOTH groups, back-to-back (latency hidden once)
        const h8 A0 = *(const h8*)&H[0][rp][col][quad * 8];
        const h8 A1 = *(const h8*)&H[0][rp][col][32 + quad * 8];
        const h8 A2 = *(const h8*)&H[0][rp][col][64 + quad * 8];
        const h8 B0 = *(const h8*)&H[1][rp][col][quad * 8];
        const h8 B1 = *(const h8*)&H[1][rp][col][32 + quad * 8];
        const h8 B2 = *(const h8*)&H[1][rp][col][64 + quad * 8];

        f4 accA[4], accB[4];
        #pragma unroll
        for (int q = 0; q < 4; ++q) {
            f4 a = __builtin_amdgcn_mfma_f32_16x16x32_f16(A0, Bf[q][0], zero4, 0, 0, 0);
            f4 b = __builtin_amdgcn_mfma_f32_16x16x32_f16(B0, Bf[q][0], zero4, 0, 0, 0);
            a = __builtin_amdgcn_mfma_f32_16x16x32_f16(A1, Bf[q][1], a, 0, 0, 0);
            b = __builtin_amdgcn_mfma_f32_16x16x32_f16(B1, Bf[q][1], b, 0, 0, 0);
            a = __builtin_amdgcn_mfma_f32_16x16x32_f16(A2, Bf[q][2], a, 0, 0, 0);
            b = __builtin_amdgcn_mfma_f32_16x16x32_f16(B2, Bf[q][2], b, 0, 0, 0);
            accA[q] = a; accB[q] = b;
        }

        // elementwise LSTM: 2 cells per group per lane (rows quad*4 + {0,1})
        #pragma unroll
        for (int r = 0; r < 2; ++r) {
            const float iiA = frcp(1.0f + fexp2(fmaf(-LOG2E,   accA[0][r], bsc[0])));
            const float ffA = frcp(1.0f + fexp2(fmaf(-LOG2E,   accA[1][r], bsc[1])));
            const float ggA = fmaf(-2.0f, frcp(1.0f + fexp2(fmaf(TWOLOG2E, accA[2][r], bsc[2]))), 1.0f);
            const float ooA = frcp(1.0f + fexp2(fmaf(-LOG2E,   accA[3][r], bsc[3])));
            cA[r] = fmaf(ffA, cA[r], iiA * ggA);
            const float thA = fmaf(-2.0f, frcp(1.0f + fexp2(TWOLOG2E * cA[r])), 1.0f);
            H[0][wp][quad * 4 + r][D_FC + w * 16 + col] = (_Float16)(ooA * thA);

            const float iiB = frcp(1.0f + fexp2(fmaf(-LOG2E,   accB[0][r], bsc[0])));
            const float ffB = frcp(1.0f + fexp2(fmaf(-LOG2E,   accB[1][r], bsc[1])));
            const float ggB = fmaf(-2.0f, frcp(1.0f + fexp2(fmaf(TWOLOG2E, accB[2][r], bsc[2]))), 1.0f);
            const float ooB = frcp(1.0f + fexp2(fmaf(-LOG2E,   accB[3][r], bsc[3])));
            cB[r] = fmaf(ffB, cB[r], iiB * ggB);
            const float thB = fmaf(-2.0f, frcp(1.0f + fexp2(TWOLOG2E * cB[r])), 1.0f);
            H[1][wp][quad * 4 + r][D_FC + w * 16 + col] = (_Float16)(ooB * thB);
        }

        // fc0 for t+1 into write buffers (both groups)
        {
            float a = b0s, b = b0s;
            #pragma unroll
            for (int i = 0; i < IN_F; ++i) {
                a = fmaf(w0c[i], xrA[i], a);
                b = fmaf(w0c[i], xrB[i], b);
            }
            H[0][wp][frow][fc] = (_Float16)a;
            H[1][wp][frow][fc] = (_Float16)b;
        }
        // prefetch x(t+2), clamped
        const int tn = (t + 2 < T_STEPS) ? (t + 2) : (T_STEPS - 1);
        #pragma unroll
        for (int i = 0; i < IN_F; ++i) {
            xrA[i] = xA[tn * IN_F + i];
            xrB[i] = xB[tn * IN_F + i];
        }

        __syncthreads();   // single barrier serves both groups
    }

    // ---- output head: h_last in buf 0 (T even); batch b at row mrow(b) ----
    if (tid < NG * GB) {
        const int g  = tid >> 3;
        const int b  = tid & 7;
        const int hr = mrow(b);
        float a = bo[0];
        #pragma unroll 8
        for (int j = 0; j < D_H; ++j)
            a = fmaf((float)H[g][0][hr][D_FC + j], Wo[j], a);
        out[bblk + g * GB + b] = a;
    }
}

extern "C" void kernel_launch(void* const* d_in, const int* in_sizes, int n_in,
                              void* d_out, int out_size, void* d_ws, size_t ws_size,
                              hipStream_t stream) {
    const float* x    = (const float*)d_in[0];
    const float* W0   = (const float*)d_in[1];
    const float* b0   = (const float*)d_in[2];
    const float* W_ih = (const float*)d_in[3];
    const float* W_hh = (const float*)d_in[4];
    const float* b_ih = (const float*)d_in[5];
    const float* b_hh = (const float*)d_in[6];
    const float* Wo   = (const float*)d_in[7];
    const float* bo   = (const float*)d_in[8];
    float* out = (float*)d_out;

    hipLaunchKernelGGL(lstm_mfma, dim3(B_TOT / (NG * GB)), dim3(256), 0, stream,
                       x, W0, b0, W_ih, W_hh, b_ih, b_hh, Wo, bo, out);
}